// Round 1
// baseline (498.700 us; speedup 1.0000x reference)
//
#include <hip/hip_runtime.h>
#include <hip/hip_bf16.h>
#include <stdint.h>
#include <stddef.h>

typedef float f32x4 __attribute__((ext_vector_type(4)));
typedef int   i32x4 __attribute__((ext_vector_type(4)));
typedef int   i32x8 __attribute__((ext_vector_type(8)));

#define FP8_MAX 448.0f
#define ACT_EPS 1e-4f
#define W_EPS   1e-6f

// ---------------- Quant activations -> packed fp8 + transposed scales ----------------
__global__ __launch_bounds__(256) void quant_x_kernel(const float* __restrict__ x,
                                                      uint8_t* __restrict__ xq,
                                                      float* __restrict__ sxT,
                                                      int M, int K) {
  const int t = threadIdx.x;
  const int l32 = t & 31;
  const int ktiles = K >> 7;
  const int tile = blockIdx.x * 8 + (t >> 5);
  const int row = tile / ktiles, kt = tile % ktiles;
  const size_t base = (size_t)row * K + (size_t)kt * 128 + l32 * 4;
  const float4 v = *(const float4*)(x + base);
  float amax = fmaxf(fmaxf(fabsf(v.x), fabsf(v.y)), fmaxf(fabsf(v.z), fabsf(v.w)));
#pragma unroll
  for (int off = 16; off > 0; off >>= 1)
    amax = fmaxf(amax, __shfl_xor(amax, off, 64));
  const float safe = fmaxf(amax, ACT_EPS);
  const float r = FP8_MAX / safe;
  int pk = __builtin_amdgcn_cvt_pk_fp8_f32(v.x * r, v.y * r, 0, false);
  pk = __builtin_amdgcn_cvt_pk_fp8_f32(v.z * r, v.w * r, pk, true);
  *(int*)(xq + base) = pk;
  if (l32 == 0) sxT[(size_t)kt * M + row] = safe / FP8_MAX;
}

// ---------------- Quant weights (128x128 blocks) -> packed fp8 + scale ----------------
__global__ __launch_bounds__(256) void quant_w_kernel(const float* __restrict__ w,
                                                      uint8_t* __restrict__ wq,
                                                      float* __restrict__ ws,
                                                      int K) {
  const int ktiles = K >> 7;
  const int nb = blockIdx.x / ktiles, kb = blockIdx.x % ktiles;
  const int t = threadIdx.x;
  const int r8 = t >> 5;
  const int c4 = (t & 31) * 4;
  const size_t rbase = (size_t)(nb * 128) * K + kb * 128 + c4;

  float4 v[16];
  float amax = 0.f;
#pragma unroll
  for (int i = 0; i < 16; ++i) {
    v[i] = *(const float4*)(w + rbase + (size_t)(i * 8 + r8) * K);
    amax = fmaxf(amax, fmaxf(fmaxf(fabsf(v[i].x), fabsf(v[i].y)),
                             fmaxf(fabsf(v[i].z), fabsf(v[i].w))));
  }
#pragma unroll
  for (int off = 32; off > 0; off >>= 1)
    amax = fmaxf(amax, __shfl_xor(amax, off, 64));
  __shared__ float sm[4];
  if ((t & 63) == 0) sm[t >> 6] = amax;
  __syncthreads();
  const float bmax = fmaxf(fmaxf(sm[0], sm[1]), fmaxf(sm[2], sm[3]));
  const float safe = fmaxf(bmax, W_EPS);
  const float r = FP8_MAX / safe;
  uint8_t* dst = wq + rbase;
#pragma unroll
  for (int i = 0; i < 16; ++i) {
    int pk = __builtin_amdgcn_cvt_pk_fp8_f32(v[i].x * r, v[i].y * r, 0, false);
    pk = __builtin_amdgcn_cvt_pk_fp8_f32(v[i].z * r, v[i].w * r, pk, true);
    *(int*)(dst + (size_t)(i * 8 + r8) * K) = pk;
  }
  if (t == 0) ws[nb * ktiles + kb] = safe / FP8_MAX;
}

// ---------------- fp8 GEMM: 128x256 tile, 3-deep counted-vmcnt pipeline ----------------
__device__ __forceinline__ void async_copy16(const void* gptr, void* lptr) {
  __builtin_amdgcn_global_load_lds(
      (const __attribute__((address_space(1))) void*)gptr,
      (__attribute__((address_space(3))) void*)lptr, 16, 0, 0);
}
__device__ __forceinline__ void async_copy4(const void* gptr, void* lptr) {
  __builtin_amdgcn_global_load_lds(
      (const __attribute__((address_space(1))) void*)gptr,
      (__attribute__((address_space(3))) void*)lptr, 4, 0, 0);
}

// 8 waves: wave = (wm 0/1) x (wn 0..3), each owns a 64x64 output sub-tile.
// LDS: 3 K-tile buffers (A 16KB + B 32KB each); chunk-XOR swizzle as before
// (slot(row,sc) holds global chunk sc^(row&7)), pre-swizzled global source so
// global_load_lds dests stay linear.
// Pipeline: iter kt issues STAGE(kt+2 -> buf[(kt+2)%3]) (6 loads/wave), computes
// buf[kt%3]; one counted s_waitcnt vmcnt + raw s_barrier per iteration.
// Activation scales: SxL[2][4][128] double-buffered per 4-kt group, staged with a
// single size-4 global_load_lds per wave (counted: +1 on group-leading iters).
__global__ __launch_bounds__(512, 2) void gemm_fp8(const uint8_t* __restrict__ A,
                                                   const uint8_t* __restrict__ B,
                                                   const float* __restrict__ sxT,
                                                   const float* __restrict__ sw,
                                                   float* __restrict__ C,
                                                   int M, int N, int K) {
  __shared__ __align__(16) uint8_t As[3][128 * 128];
  __shared__ __align__(16) uint8_t Bs[3][256 * 128];
  __shared__ float SxL[2][4][128];
  __shared__ float SwL[2][32];

  const int t = threadIdx.x;
  const int wave = t >> 6, lane = t & 63;
  const int fr = lane & 15, fq = lane >> 4;
  const int wm = (wave >> 2) * 64;   // M-offset within 128
  const int wn = (wave & 3) * 64;    // N-offset within 256
  const int ktiles = K >> 7;         // 32
  const int gx = N >> 8;             // 16

  // XCD-aware bijective swizzle (nwg % 8 == 0); bx fastest within an XCD chunk
  // so consecutive blocks on one XCD share the same 512KB A-panel in L2.
  const int nwg = gridDim.x;
  const int lin = blockIdx.x;
  const int swzb = (lin & 7) * (nwg >> 3) + (lin >> 3);
  const int bx = swzb % gx, by = swzb / gx;
  const int m0 = by * 128, n0 = bx * 256;

  // ---- prologue (uncounted region): weight scales for both n-blocks, all kt ----
  if (t < 64) {
    const int nb = t >> 5, kk = t & 31;
    SwL[nb][kk] = sw[((n0 >> 7) + nb) * ktiles + kk];
  }
  __syncthreads();

  // ---- per-thread pre-swizzled staging sources (only kt*128 varies per iter) ----
  const uint8_t* sA[2];
#pragma unroll
  for (int r = 0; r < 2; ++r) {
    const int ch = r * 512 + t, row = ch >> 3, gs = (ch & 7) ^ (row & 7);
    sA[r] = A + (size_t)(m0 + row) * K + gs * 16;
  }
  const uint8_t* sB[4];
#pragma unroll
  for (int r = 0; r < 4; ++r) {
    const int ch = r * 512 + t, row = ch >> 3, gs = (ch & 7) ^ (row & 7);
    sB[r] = B + (size_t)(n0 + row) * K + gs * 16;
  }
  const float* sSx = sxT + (size_t)(t >> 7) * M + m0 + (t & 127);
  const int nbl = (wave & 3) >> 1;   // which 128-wide weight block this wave sits in

  // ---- per-thread fragment LDS byte offsets (swizzled reads) ----
  uint32_t aoff[4][2], boff[4][2];
#pragma unroll
  for (int i = 0; i < 4; ++i) {
    const int ra = wm + i * 16 + fr, rs = ra & 7;
    aoff[i][0] = ra * 128 + ((((fq << 1)) ^ rs) << 4);
    aoff[i][1] = ra * 128 + ((((fq << 1) | 1) ^ rs) << 4);
  }
#pragma unroll
  for (int j = 0; j < 4; ++j) {
    const int rb = wn + j * 16 + fr, rs = rb & 7;
    boff[j][0] = rb * 128 + ((((fq << 1)) ^ rs) << 4);
    boff[j][1] = rb * 128 + ((((fq << 1) | 1) ^ rs) << 4);
  }

  f32x4 acc[4][4] = {};

  auto STAGE = [&](int kt, int c) {    // 6 counted loads per wave
#pragma unroll
    for (int r = 0; r < 2; ++r)
      async_copy16(sA[r] + (size_t)kt * 128, (char*)As[c] + r * 8192 + wave * 1024);
#pragma unroll
    for (int r = 0; r < 4; ++r)
      async_copy16(sB[r] + (size_t)kt * 128, (char*)Bs[c] + r * 8192 + wave * 1024);
  };
  auto SXSTAGE = [&](int grp) {        // 1 counted load per wave
    async_copy4(sSx + (size_t)grp * 4 * M, (char*)SxL[grp & 1] + wave * 256);
  };

  // ---- counted prologue: scales(grp0) + K-tiles 0,1 in flight; land SxL0+tile0 ----
  SXSTAGE(0);
  STAGE(0, 0);
  STAGE(1, 1);
  asm volatile("s_waitcnt vmcnt(6)" ::: "memory");
  __builtin_amdgcn_s_barrier();
  asm volatile("" ::: "memory");

// One iteration. Wait constants (per-wave outstanding after the wait):
//   steady j=0: drain stage(kt+1); leaves [SXSTAGE(g+1) + stage(kt+2)] = 7
//   steady j>0: leaves [stage(kt+2)] = 6
//   tail kt=30: drain stage(31) -> 0; kt=31: no wait (epilogue follows).
#define KSTEP(G, JJ, VMC, DO_SX, DO_ST, DO_WAIT)                                  \
  {                                                                               \
    const int kt_ = (G) * 4 + (JJ);                                               \
    if (DO_SX) SXSTAGE((G) + 1);                                                  \
    if (DO_ST) STAGE(kt_ + 2, (kt_ + 2) % 3);                                     \
    const int c_ = kt_ % 3;                                                       \
    const uint8_t* ab_ = As[c_];                                                  \
    const uint8_t* bb_ = Bs[c_];                                                  \
    i32x8 af_[4], bf_[4];                                                         \
    _Pragma("unroll")                                                             \
    for (int i_ = 0; i_ < 4; ++i_) {                                              \
      const i32x4 lo_ = *(const i32x4*)(ab_ + aoff[i_][0]);                       \
      const i32x4 hi_ = *(const i32x4*)(ab_ + aoff[i_][1]);                       \
      af_[i_] = __builtin_shufflevector(lo_, hi_, 0, 1, 2, 3, 4, 5, 6, 7);        \
    }                                                                             \
    _Pragma("unroll")                                                             \
    for (int j_ = 0; j_ < 4; ++j_) {                                              \
      const i32x4 lo_ = *(const i32x4*)(bb_ + boff[j_][0]);                       \
      const i32x4 hi_ = *(const i32x4*)(bb_ + boff[j_][1]);                       \
      bf_[j_] = __builtin_shufflevector(lo_, hi_, 0, 1, 2, 3, 4, 5, 6, 7);        \
    }                                                                             \
    const float swv_ = SwL[nbl][kt_];                                             \
    f32x4 sf_[4];                                                                 \
    _Pragma("unroll")                                                             \
    for (int i_ = 0; i_ < 4; ++i_)                                                \
      sf_[i_] = (*(const f32x4*)&SxL[(G) & 1][(JJ)][wm + i_ * 16 + fq * 4]) * swv_; \
    __builtin_amdgcn_s_setprio(1);                                                \
    _Pragma("unroll")                                                             \
    for (int i_ = 0; i_ < 4; ++i_) {                                              \
      _Pragma("unroll")                                                           \
      for (int j_ = 0; j_ < 4; ++j_) {                                            \
        const f32x4 z_ = {0.f, 0.f, 0.f, 0.f};                                    \
        const f32x4 p_ = __builtin_amdgcn_mfma_scale_f32_16x16x128_f8f6f4(        \
            af_[i_], bf_[j_], z_, 0, 0, 0, 0x7F7F7F7F, 0, 0x7F7F7F7F);            \
        acc[i_][j_] += p_ * sf_[i_];                                              \
      }                                                                           \
    }                                                                             \
    __builtin_amdgcn_s_setprio(0);                                                \
    if (DO_WAIT) {                                                                \
      asm volatile("s_waitcnt vmcnt(" #VMC ")" ::: "memory");                     \
      __builtin_amdgcn_s_barrier();                                               \
      asm volatile("" ::: "memory");                                              \
    }                                                                             \
  }

#pragma unroll 1
  for (int g = 0; g < 7; ++g) {
    KSTEP(g, 0, 7, 1, 1, 1)
    KSTEP(g, 1, 6, 0, 1, 1)
    KSTEP(g, 2, 6, 0, 1, 1)
    KSTEP(g, 3, 6, 0, 1, 1)
  }
  // tail group g=7: no more scale groups; stages 30,31 then drain
  KSTEP(7, 0, 6, 0, 1, 1)
  KSTEP(7, 1, 6, 0, 1, 1)
  KSTEP(7, 2, 0, 0, 0, 1)
  KSTEP(7, 3, 0, 0, 0, 0)
#undef KSTEP

  // Epilogue: D layout col = lane&15, row = fq*4 + reg.
#pragma unroll
  for (int i = 0; i < 4; ++i) {
    const int row0 = m0 + wm + i * 16 + fq * 4;
#pragma unroll
    for (int j = 0; j < 4; ++j) {
      const int col = n0 + wn + j * 16 + fr;
      float* cp = C + (size_t)row0 * N + col;
#pragma unroll
      for (int r = 0; r < 4; ++r) cp[(size_t)r * N] = acc[i][j][r];
    }
  }
}

extern "C" void kernel_launch(void* const* d_in, const int* in_sizes, int n_in,
                              void* d_out, int out_size, void* d_ws, size_t ws_size,
                              hipStream_t stream) {
  const float* x = (const float*)d_in[0];    // [M, K] fp32
  const float* w = (const float*)d_in[1];    // [N, K] fp32
  float* out = (float*)d_out;                // [M, N] fp32

  const int K = 4096;
  const int M = in_sizes[0] / K;  // 8192
  const int N = in_sizes[1] / K;  // 4096
  const int ktiles = K / 128;

  uint8_t* xq = (uint8_t*)d_ws;                       // M*K fp8
  uint8_t* wq = xq + (size_t)M * K;                   // N*K fp8
  float*   sxT = (float*)(wq + (size_t)N * K);        // [K/128, M]
  float*   ws  = sxT + (size_t)ktiles * M;            // [N/128, K/128]

  quant_x_kernel<<<(M * ktiles) / 8, 256, 0, stream>>>(x, xq, sxT, M, K);
  quant_w_kernel<<<(N / 128) * ktiles, 256, 0, stream>>>(w, wq, ws, K);
  const int nblocks = (M / 128) * (N / 256);          // 1024, % 8 == 0
  gemm_fp8<<<nblocks, 512, 0, stream>>>(xq, wq, sxT, ws, out, M, N, K);
}